// Round 8
// baseline (224.171 us; speedup 1.0000x reference)
//
#include <hip/hip_runtime.h>
#include <cmath>

typedef unsigned short u16;
typedef __attribute__((ext_vector_type(8))) short bf16x8;
typedef __attribute__((ext_vector_type(4))) float f32x4;
typedef __attribute__((ext_vector_type(8))) unsigned short u16x8;

#define B_  32
#define N_  1024
#define L_  256
#define S_  8
#define DT_ 512
#define BAND_ 16

__device__ __forceinline__ u16 f2bf(float f) {
  union { float f; unsigned u; } x; x.f = f;
  unsigned r = (x.u + 0x7fffu + ((x.u >> 16) & 1u)) >> 16;
  return (u16)r;
}
__device__ __forceinline__ float bf2f(u16 h) {
  union { unsigned u; float f; } x; x.u = ((unsigned)h) << 16;
  return x.f;
}
// packed f32x2 -> bf16x2 (RNE), 1 instr
__device__ __forceinline__ unsigned cvtpk(float lo, float hi) {
  unsigned r;
  asm volatile("v_cvt_pk_bf16_f32 %0, %1, %2" : "=v"(r) : "v"(lo), "v"(hi));
  return r;
}

// ---------------------------------------------------------------------------
// All small weights in one launch. float4 counts:
// emb 131072 | wq 65536 | wk 65536 | wv 65536 | wv2t 65536 | pwk 65536
// ---------------------------------------------------------------------------
__global__ __launch_bounds__(256) void cvt_weights(
    const float* __restrict__ e, const float* __restrict__ q,
    const float* __restrict__ k, const float* __restrict__ v,
    const float* __restrict__ t, const float* __restrict__ pw,
    u16* __restrict__ eo, u16* __restrict__ qo, u16* __restrict__ kvo,
    u16* __restrict__ to, u16* __restrict__ po) {
  int i = blockIdx.x * 256 + threadIdx.x;
  const float* src; u16* dst; int soff, doff;
  if (i < 131072)      { src = e;  dst = eo;  soff = i;          doff = soff; }
  else if (i < 196608) { src = q;  dst = qo;  soff = i - 131072; doff = soff; }
  else if (i < 262144) { src = k;  dst = kvo; soff = i - 196608; doff = soff; }
  else if (i < 327680) { src = v;  dst = kvo; soff = i - 262144; doff = soff + 65536; }
  else if (i < 393216) { src = t;  dst = to;  soff = i - 327680; doff = soff; }
  else                 { src = pw; dst = po;  soff = i - 393216; doff = soff; }
  float4 vv = ((const float4*)src)[soff];
  ushort4 o;
  o.x = f2bf(vv.x); o.y = f2bf(vv.y); o.z = f2bf(vv.z); o.w = f2bf(vv.w);
  ((ushort4*)dst)[doff] = o;
}

// ---------------------------------------------------------------------------
// K1: per (b,l): gather emb rows, depthwise conv (k=3, SAME, cross-corr),
// silu, mean over s -> shm (bf16); meanE -> mbuf (f32)
// ---------------------------------------------------------------------------
__global__ __launch_bounds__(256) void text_front(
    const int* __restrict__ ids, const float* __restrict__ emb,
    const float* __restrict__ dwk, u16* __restrict__ shm,
    float* __restrict__ mbuf) {
  int bl = blockIdx.x;
  int tid = threadIdx.x;
  __shared__ int sid[S_];
  if (tid < S_) sid[tid] = ids[bl * S_ + tid];
  __syncthreads();
  for (int c = tid; c < DT_; c += 256) {
    float x[S_];
#pragma unroll
    for (int s = 0; s < S_; ++s) x[s] = emb[(size_t)sid[s] * DT_ + c];
    float k0 = dwk[c * 3 + 0], k1 = dwk[c * 3 + 1], k2 = dwk[c * 3 + 2];
    float me = 0.f, sh = 0.f;
#pragma unroll
    for (int s = 0; s < S_; ++s) {
      float xm = (s > 0) ? x[s - 1] : 0.0f;
      float xp = (s < S_ - 1) ? x[s + 1] : 0.0f;
      float h = k0 * xm + k1 * x[s] + k2 * xp;
      float si = h / (1.0f + expf(-h));  // silu
      me += x[s];
      sh += si;
    }
    shm[(size_t)bl * DT_ + c] = f2bf(sh * (1.0f / S_));
    mbuf[(size_t)bl * DT_ + c] = me * (1.0f / S_);
  }
}

// ---------------------------------------------------------------------------
// KV GEMM with fused f32->bf16 on A: C_bf16[m][n] = sum_k A_f32[m][k]*B[n][k]
// Tile 128x128, BK=32, 256 thr (2x2 waves). A reg-staged (f32 loads issued
// before MFMA phase, cvt_pk + ds_write after), B via global_load_lds. 2-phase.
// ---------------------------------------------------------------------------
__global__ __launch_bounds__(256) void gemm_kv_f32a(
    const float* __restrict__ A, const u16* __restrict__ B,
    u16* __restrict__ Cb, int M, int N, int K) {
  __shared__ u16 As[8192];  // [2][128][32]
  __shared__ u16 Bs[8192];
  const int tid = threadIdx.x;
  const int w = tid >> 6;
  const int lane = tid & 63;

  const int gx = gridDim.x;
  const int bid = blockIdx.y * gx + blockIdx.x;
  const int nwg = gx * gridDim.y;
  const int logical = (bid & 7) * (nwg >> 3) + (bid >> 3);
  const int bm = (logical / gx) << 7;
  const int bn = (logical % gx) << 7;
  const int wr = w >> 1, wc = w & 1;

  // A reg-staging: thread covers row=tid>>1 (0..127), k-half=(tid&1)*16
  const int arow = tid >> 1;
  const int ahalf = (tid & 1) << 4;
  const float* Ap = A + (size_t)(bm + arow) * K + ahalf;
  const int awoff = arow * 32 + ahalf;  // u16 offset in As half-buffer

  // B staging via global_load_lds
  const int r0 = (w << 4) + (lane >> 2);
  const int kc = (lane & 3) << 3;
  const u16* Bg0 = B + (size_t)(bn + r0) * K + kc;
  const u16* Bg1 = Bg0 + (size_t)64 * K;

  int aoff[4], boff[4];
#pragma unroll
  for (int m = 0; m < 4; ++m)
    aoff[m] = (((wr << 6) + (m << 4) + (lane & 15)) << 5) + ((lane >> 4) << 3);
#pragma unroll
  for (int n = 0; n < 4; ++n)
    boff[n] = (((wc << 6) + (n << 4) + (lane & 15)) << 5) + ((lane >> 4) << 3);

  f32x4 acc[4][4];
#pragma unroll
  for (int m = 0; m < 4; ++m)
#pragma unroll
    for (int n = 0; n < 4; ++n) acc[m][n] = (f32x4){0.f, 0.f, 0.f, 0.f};

  float4 ar0, ar1, ar2, ar3;
#define LOADA(kt)                              \
  {                                            \
    ar0 = *(const float4*)(Ap + (kt));         \
    ar1 = *(const float4*)(Ap + (kt) + 4);     \
    ar2 = *(const float4*)(Ap + (kt) + 8);     \
    ar3 = *(const float4*)(Ap + (kt) + 12);    \
  }
#define WRITEA(buf)                                              \
  {                                                              \
    uint4 q0, q1;                                                \
    q0.x = cvtpk(ar0.x, ar0.y); q0.y = cvtpk(ar0.z, ar0.w);      \
    q0.z = cvtpk(ar1.x, ar1.y); q0.w = cvtpk(ar1.z, ar1.w);      \
    q1.x = cvtpk(ar2.x, ar2.y); q1.y = cvtpk(ar2.z, ar2.w);      \
    q1.z = cvtpk(ar3.x, ar3.y); q1.w = cvtpk(ar3.z, ar3.w);      \
    *(uint4*)(As + (buf) * 4096 + awoff) = q0;                   \
    *(uint4*)(As + (buf) * 4096 + awoff + 8) = q1;               \
  }
#define STAGEB(buf, kt)                                                       \
  {                                                                           \
    u16* bs_ = Bs + (buf) * 4096 + (w << 9);                                  \
    __builtin_amdgcn_global_load_lds(                                         \
        (const __attribute__((address_space(1))) void*)(Bg0 + (kt)),          \
        (__attribute__((address_space(3))) void*)bs_, 16, 0, 0);              \
    __builtin_amdgcn_global_load_lds(                                         \
        (const __attribute__((address_space(1))) void*)(Bg1 + (kt)),          \
        (__attribute__((address_space(3))) void*)(bs_ + 2048), 16, 0, 0);     \
  }

  const int nt = K >> 5;
  LOADA(0);
  STAGEB(0, 0);
  WRITEA(0);
  __syncthreads();
  int cur = 0;
  for (int t = 0; t < nt; ++t) {
    if (t + 1 < nt) LOADA((t + 1) << 5);  // latency hides under MFMA below
    const u16* Ab = As + cur * 4096;
    const u16* Bb = Bs + cur * 4096;
    bf16x8 af[4], bfr[4];
#pragma unroll
    for (int m = 0; m < 4; ++m) af[m] = *(const bf16x8*)(Ab + aoff[m]);
#pragma unroll
    for (int n = 0; n < 4; ++n) bfr[n] = *(const bf16x8*)(Bb + boff[n]);
#pragma unroll
    for (int m = 0; m < 4; ++m)
#pragma unroll
      for (int n = 0; n < 4; ++n)
        acc[m][n] = __builtin_amdgcn_mfma_f32_16x16x32_bf16(
            af[m], bfr[n], acc[m][n], 0, 0, 0);
    if (t + 1 < nt) {
      WRITEA(cur ^ 1);
      STAGEB(cur ^ 1, (t + 1) << 5);
    }
    __syncthreads();
    cur ^= 1;
  }
#undef LOADA
#undef WRITEA
#undef STAGEB

  const int rb = bm + (wr << 6) + ((lane >> 4) << 2);
  const int cb = bn + (wc << 6) + (lane & 15);
#pragma unroll
  for (int m = 0; m < 4; ++m)
#pragma unroll
    for (int n = 0; n < 4; ++n) {
      int col = cb + (n << 4);
#pragma unroll
      for (int j = 0; j < 4; ++j) {
        size_t idx = (size_t)(rb + (m << 4) + j) * N + col;
        Cb[idx] = f2bf(acc[m][n][j]);
      }
    }
}

// ---------------------------------------------------------------------------
// bf16 MFMA GEMM, 128x128 tile (used for cls). 2-phase + XCD swizzle.
// ---------------------------------------------------------------------------
template <bool ACC, bool WF32, bool WBF16>
__global__ __launch_bounds__(256) void gemm_mfma(
    const u16* __restrict__ A, const u16* __restrict__ B,
    float* __restrict__ C, u16* __restrict__ Cb, int M, int N, int K) {
  __shared__ u16 As[8192];
  __shared__ u16 Bs[8192];
  const int tid = threadIdx.x;
  const int w = tid >> 6;
  const int lane = tid & 63;

  const int gx = gridDim.x;
  const int bid = blockIdx.y * gx + blockIdx.x;
  const int nwg = gx * gridDim.y;
  const int logical = (bid & 7) * (nwg >> 3) + (bid >> 3);
  const int bm = (logical / gx) << 7;
  const int bn = (logical % gx) << 7;
  const int wr = w >> 1, wc = w & 1;

  const int r0 = (w << 4) + (lane >> 2);
  const int kc = (lane & 3) << 3;
  const u16* Ag0 = A + (size_t)(bm + r0) * K + kc;
  const u16* Ag1 = Ag0 + (size_t)64 * K;
  const u16* Bg0 = B + (size_t)(bn + r0) * K + kc;
  const u16* Bg1 = Bg0 + (size_t)64 * K;

  int aoff[4], boff[4];
#pragma unroll
  for (int m = 0; m < 4; ++m)
    aoff[m] = (((wr << 6) + (m << 4) + (lane & 15)) << 5) + ((lane >> 4) << 3);
#pragma unroll
  for (int n = 0; n < 4; ++n)
    boff[n] = (((wc << 6) + (n << 4) + (lane & 15)) << 5) + ((lane >> 4) << 3);

  f32x4 acc[4][4];
#pragma unroll
  for (int m = 0; m < 4; ++m)
#pragma unroll
    for (int n = 0; n < 4; ++n) acc[m][n] = (f32x4){0.f, 0.f, 0.f, 0.f};

#define STAGE(buf, kt)                                                        \
  {                                                                           \
    u16* as_ = As + (buf) * 4096 + (w << 9);                                  \
    u16* bs_ = Bs + (buf) * 4096 + (w << 9);                                  \
    __builtin_amdgcn_global_load_lds(                                         \
        (const __attribute__((address_space(1))) void*)(Ag0 + (kt)),          \
        (__attribute__((address_space(3))) void*)as_, 16, 0, 0);              \
    __builtin_amdgcn_global_load_lds(                                         \
        (const __attribute__((address_space(1))) void*)(Ag1 + (kt)),          \
        (__attribute__((address_space(3))) void*)(as_ + 2048), 16, 0, 0);     \
    __builtin_amdgcn_global_load_lds(                                         \
        (const __attribute__((address_space(1))) void*)(Bg0 + (kt)),          \
        (__attribute__((address_space(3))) void*)bs_, 16, 0, 0);              \
    __builtin_amdgcn_global_load_lds(                                         \
        (const __attribute__((address_space(1))) void*)(Bg1 + (kt)),          \
        (__attribute__((address_space(3))) void*)(bs_ + 2048), 16, 0, 0);     \
  }

  const int nt = K >> 5;
  STAGE(0, 0);
  __syncthreads();
  int cur = 0;
  for (int t = 0; t < nt; ++t) {
    if (t + 1 < nt) STAGE(cur ^ 1, (t + 1) << 5);
    const u16* Ab = As + cur * 4096;
    const u16* Bb = Bs + cur * 4096;
    bf16x8 af[4], bfr[4];
#pragma unroll
    for (int m = 0; m < 4; ++m) af[m] = *(const bf16x8*)(Ab + aoff[m]);
#pragma unroll
    for (int n = 0; n < 4; ++n) bfr[n] = *(const bf16x8*)(Bb + boff[n]);
#pragma unroll
    for (int m = 0; m < 4; ++m)
#pragma unroll
      for (int n = 0; n < 4; ++n)
        acc[m][n] = __builtin_amdgcn_mfma_f32_16x16x32_bf16(
            af[m], bfr[n], acc[m][n], 0, 0, 0);
    __syncthreads();
    cur ^= 1;
  }
#undef STAGE

  const int rb = bm + (wr << 6) + ((lane >> 4) << 2);
  const int cb = bn + (wc << 6) + (lane & 15);
#pragma unroll
  for (int m = 0; m < 4; ++m)
#pragma unroll
    for (int n = 0; n < 4; ++n) {
      int col = cb + (n << 4);
#pragma unroll
      for (int j = 0; j < 4; ++j) {
        size_t idx = (size_t)(rb + (m << 4) + j) * N + col;
        float v = acc[m][n][j];
        if (ACC) v += C[idx];
        if (WF32) C[idx] = v;
        if (WBF16) Cb[idx] = f2bf(v);
      }
    }
}

// ---------------------------------------------------------------------------
// bf16 MFMA GEMM, 128x64 tile for N=512 GEMMs (512 blocks -> 2/CU).
// 4 waves stacked on M (wave w: rows w*32..w*32+31), frags 2(M)x4(N).
// LDS: A 2x8KB + B 2x4KB = 24KB.
// ---------------------------------------------------------------------------
template <bool ACC, bool WF32, bool WBF16>
__global__ __launch_bounds__(256) void gemm_n64(
    const u16* __restrict__ A, const u16* __restrict__ B,
    float* __restrict__ C, u16* __restrict__ Cb, int M, int N, int K) {
  __shared__ u16 As[8192];  // [2][128][32]
  __shared__ u16 Bs[4096];  // [2][64][32]
  const int tid = threadIdx.x;
  const int w = tid >> 6;
  const int lane = tid & 63;

  const int gx = gridDim.x;  // N/64
  const int bid = blockIdx.y * gx + blockIdx.x;
  const int nwg = gx * gridDim.y;
  const int logical = (bid & 7) * (nwg >> 3) + (bid >> 3);
  const int bm = (logical / gx) << 7;
  const int bn = (logical % gx) << 6;

  const int r0 = (w << 4) + (lane >> 2);
  const int kc = (lane & 3) << 3;
  const u16* Ag0 = A + (size_t)(bm + r0) * K + kc;
  const u16* Ag1 = Ag0 + (size_t)64 * K;
  const u16* Bg0 = B + (size_t)(bn + r0) * K + kc;

  int aoff[2], boff[4];
#pragma unroll
  for (int m = 0; m < 2; ++m)
    aoff[m] = (((w << 5) + (m << 4) + (lane & 15)) << 5) + ((lane >> 4) << 3);
#pragma unroll
  for (int n = 0; n < 4; ++n)
    boff[n] = (((n << 4) + (lane & 15)) << 5) + ((lane >> 4) << 3);

  f32x4 acc[2][4];
#pragma unroll
  for (int m = 0; m < 2; ++m)
#pragma unroll
    for (int n = 0; n < 4; ++n) acc[m][n] = (f32x4){0.f, 0.f, 0.f, 0.f};

#define STAGE(buf, kt)                                                        \
  {                                                                           \
    u16* as_ = As + (buf) * 4096 + (w << 9);                                  \
    u16* bs_ = Bs + (buf) * 2048 + (w << 9);                                  \
    __builtin_amdgcn_global_load_lds(                                         \
        (const __attribute__((address_space(1))) void*)(Ag0 + (kt)),          \
        (__attribute__((address_space(3))) void*)as_, 16, 0, 0);              \
    __builtin_amdgcn_global_load_lds(                                         \
        (const __attribute__((address_space(1))) void*)(Ag1 + (kt)),          \
        (__attribute__((address_space(3))) void*)(as_ + 2048), 16, 0, 0);     \
    __builtin_amdgcn_global_load_lds(                                         \
        (const __attribute__((address_space(1))) void*)(Bg0 + (kt)),          \
        (__attribute__((address_space(3))) void*)bs_, 16, 0, 0);              \
  }

  const int nt = K >> 5;
  STAGE(0, 0);
  __syncthreads();
  int cur = 0;
  for (int t = 0; t < nt; ++t) {
    if (t + 1 < nt) STAGE(cur ^ 1, (t + 1) << 5);
    const u16* Ab = As + cur * 4096;
    const u16* Bb = Bs + cur * 2048;
    bf16x8 af[2], bfr[4];
#pragma unroll
    for (int m = 0; m < 2; ++m) af[m] = *(const bf16x8*)(Ab + aoff[m]);
#pragma unroll
    for (int n = 0; n < 4; ++n) bfr[n] = *(const bf16x8*)(Bb + boff[n]);
#pragma unroll
    for (int m = 0; m < 2; ++m)
#pragma unroll
      for (int n = 0; n < 4; ++n)
        acc[m][n] = __builtin_amdgcn_mfma_f32_16x16x32_bf16(
            af[m], bfr[n], acc[m][n], 0, 0, 0);
    __syncthreads();
    cur ^= 1;
  }
#undef STAGE

  const int rb = bm + (w << 5) + ((lane >> 4) << 2);
  const int cb = bn + (lane & 15);
#pragma unroll
  for (int m = 0; m < 2; ++m)
#pragma unroll
    for (int n = 0; n < 4; ++n) {
      int col = cb + (n << 4);
#pragma unroll
      for (int j = 0; j < 4; ++j) {
        size_t idx = (size_t)(rb + (m << 4) + j) * N + col;
        float v = acc[m][n][j];
        if (ACC) v += C[idx];
        if (WF32) C[idx] = v;
        if (WBF16) Cb[idx] = f2bf(v);
      }
    }
}

// ---------------------------------------------------------------------------
// LayerNorm over DT=512 per row; writes bf16 q_txt
// ---------------------------------------------------------------------------
__global__ __launch_bounds__(256) void ln_kernel(
    const float* __restrict__ m, const float* __restrict__ g,
    const float* __restrict__ bta, u16* __restrict__ q) {
  int row = blockIdx.x;
  int tid = threadIdx.x;
  float v0 = m[(size_t)row * 512 + tid];
  float v1 = m[(size_t)row * 512 + 256 + tid];
  __shared__ float red[4], red2[4];
  float s = v0 + v1;
#pragma unroll
  for (int d = 32; d; d >>= 1) s += __shfl_xor(s, d);
  if ((tid & 63) == 0) red[tid >> 6] = s;
  __syncthreads();
  float mu = (red[0] + red[1] + red[2] + red[3]) * (1.0f / 512.0f);
  float d0 = v0 - mu, d1 = v1 - mu;
  float s2 = d0 * d0 + d1 * d1;
#pragma unroll
  for (int d = 32; d; d >>= 1) s2 += __shfl_xor(s2, d);
  if ((tid & 63) == 0) red2[tid >> 6] = s2;
  __syncthreads();
  float var = (red2[0] + red2[1] + red2[2] + red2[3]) * (1.0f / 512.0f);
  float r = rsqrtf(var + 1e-5f);
  q[(size_t)row * 512 + tid] = f2bf(d0 * r * g[tid] + bta[tid]);
  q[(size_t)row * 512 + 256 + tid] = f2bf(d1 * r * g[tid + 256] + bta[tid + 256]);
}

// ---------------------------------------------------------------------------
// MFMA banded attention. Block = (b, 16 l), 512 threads = 8 waves.
// ---------------------------------------------------------------------------
__global__ __launch_bounds__(512) void attn_kernel(
    const u16* __restrict__ Qb, const u16* __restrict__ KV,
    const float* __restrict__ alpha_p, float* __restrict__ A,
    u16* __restrict__ Fv) {
  __shared__ u16 KV_s[96 * 512];   // 96 KB, K then reused for V
  __shared__ u16 Q_s[16 * 520];    // padded stride 520 u16
  __shared__ float S_s[16 * 100];  // logits then attention weights

  const int bid = blockIdx.x;
  const int logical = (bid & 7) * 64 + (bid >> 3);
  const int b = logical >> 4, lg = logical & 15;
  const int l0 = lg * 16;
  const int tid = threadIdx.x;
  const int w = tid >> 6, lane = tid & 63;
  const float al = *alpha_p;

  const int c_min = (1023 * l0) / 255;
  const int kb0 = min(max(c_min - BAND_, 0), N_ - 96);

  {
    const size_t rowb = (size_t)(b * N_ + kb0);
    for (int rr = 0; rr < 12; ++rr) {
      const int r = w * 12 + rr;
      const u16* src = KV + (rowb + r) * 1024 + ((lane * 8) ^ ((r & 7) << 3));
      u16* dst = KV_s + r * 512;
      __builtin_amdgcn_global_load_lds(
          (const __attribute__((address_space(1))) void*)src,
          (__attribute__((address_space(3))) void*)dst, 16, 0, 0);
    }
  }
  {
    const int r = tid >> 5;
    const u16* qrow = Qb + (size_t)(b * L_ + l0 + r) * 512;
#pragma unroll
    for (int h = 0; h < 2; ++h) {
      const int ch = (tid & 31) + h * 32;
      u16x8 v = *(const u16x8*)(qrow + ch * 8);
      *(u16x8*)(Q_s + r * 520 + ch * 8) = v;
    }
  }
  __syncthreads();

  if (w < 6) {
    f32x4 acc = {0.f, 0.f, 0.f, 0.f};
    const int arow = (lane & 15) * 520 + ((lane >> 4) << 3);
    const int key = w * 16 + (lane & 15);
    const int swz = (key & 7) << 3;
    for (int ks = 0; ks < 16; ++ks) {
      bf16x8 aq = *(const bf16x8*)(Q_s + arow + ks * 32);
      bf16x8 bk =
          *(const bf16x8*)(KV_s + key * 512 + ((ks * 32 + ((lane >> 4) << 3)) ^ swz));
      acc = __builtin_amdgcn_mfma_f32_16x16x32_bf16(aq, bk, acc, 0, 0, 0);
    }
#pragma unroll
    for (int j = 0; j < 4; ++j)
      S_s[((lane >> 4) * 4 + j) * 100 + w * 16 + (lane & 15)] = acc[j];
  }
  __syncthreads();

  {
    const size_t rowb = (size_t)(b * N_ + kb0);
    for (int rr = 0; rr < 12; ++rr) {
      const int r = w * 12 + rr;
      const u16* src =
          KV + (rowb + r) * 1024 + 512 + ((lane * 8) ^ ((r & 7) << 3));
      u16* dst = KV_s + r * 512;
      __builtin_amdgcn_global_load_lds(
          (const __attribute__((address_space(1))) void*)src,
          (__attribute__((address_space(3))) void*)dst, 16, 0, 0);
    }
  }

#pragma unroll
  for (int rr = 0; rr < 2; ++rr) {
    const int l = 2 * w + rr;
    const int c = (1023 * (l0 + l)) / 255;
    const int g0 = kb0 + lane, g1 = kb0 + 64 + lane;
    const bool v0 = (g0 >= c - BAND_) && (g0 <= c + BAND_);
    const bool v1 = (lane < 32) && (g1 >= c - BAND_) && (g1 <= c + BAND_);
    const float sc = 0.044194173824159216f;
    float x0 = v0 ? S_s[l * 100 + lane] * sc +
                        al * ((float)(c - g0) * (1.0f / 16.000001f))
                  : -INFINITY;
    float x1 = v1 ? S_s[l * 100 + 64 + lane] * sc +
                        al * ((float)(c - g1) * (1.0f / 16.000001f))
                  : -INFINITY;
    float mx = fmaxf(x0, x1);
#pragma unroll
    for (int d = 32; d; d >>= 1) mx = fmaxf(mx, __shfl_xor(mx, d));
    float e0 = v0 ? expf(x0 - mx) : 0.0f;
    float e1 = v1 ? expf(x1 - mx) : 0.0f;
    float sm = e0 + e1;
#pragma unroll
    for (int d = 32; d; d >>= 1) sm += __shfl_xor(sm, d);
    const float inv = 1.0f / sm;
    S_s[l * 100 + lane] = e0 * inv;
    if (lane < 32) S_s[l * 100 + 64 + lane] = e1 * inv;
    const int lo = max(0, c - BAND_), hi = min(N_ - 1, c + BAND_);
    float* Arow = A + (size_t)(b * L_ + l0 + l) * N_;
#pragma unroll
    for (int p4 = 0; p4 < 4; ++p4) {
      const int p = (p4 * 64 + lane) * 4;
      float4 v;
      v.x = (p + 0 >= lo && p + 0 <= hi) ? S_s[l * 100 + p + 0 - kb0] : 0.0f;
      v.y = (p + 1 >= lo && p + 1 <= hi) ? S_s[l * 100 + p + 1 - kb0] : 0.0f;
      v.z = (p + 2 >= lo && p + 2 <= hi) ? S_s[l * 100 + p + 2 - kb0] : 0.0f;
      v.w = (p + 3 >= lo && p + 3 <= hi) ? S_s[l * 100 + p + 3 - kb0] : 0.0f;
      ((float4*)Arow)[p4 * 64 + lane] = v;
    }
  }
  __syncthreads();

#pragma unroll
  for (int rr = 0; rr < 2; ++rr) {
    const int l = 2 * w + rr;
    const int c = (1023 * (l0 + l)) / 255;
    const int jlo = max(0, c - BAND_) - kb0, jhi = min(N_ - 1, c + BAND_) - kb0;
    float acc[8] = {};
    for (int j = jlo; j <= jhi; ++j) {
      const float avj = S_s[l * 100 + j];
      const u16x8 v =
          *(const u16x8*)(KV_s + j * 512 + ((lane * 8) ^ ((j & 7) << 3)));
#pragma unroll
      for (int t = 0; t < 8; ++t) acc[t] += avj * bf2f(v[t]);
    }
    u16x8 fo;
#pragma unroll
    for (int t = 0; t < 8; ++t) fo[t] = f2bf(acc[t]);
    *(u16x8*)(Fv + (size_t)(b * L_ + l0 + l) * 512 + lane * 8) = fo;
  }
}

// ---------------------------------------------------------------------------
extern "C" void kernel_launch(void* const* d_in, const int* in_sizes, int n_in,
                              void* d_out, int out_size, void* d_ws,
                              size_t ws_size, hipStream_t stream) {
  const float* vis = (const float*)d_in[0];    // [32,1024,512]
  const int* ids = (const int*)d_in[1];        // [32,256,8]
  const float* emb = (const float*)d_in[2];    // [1024,512]
  const float* wq = (const float*)d_in[3];     // [512,512]
  const float* wk = (const float*)d_in[4];     // [512,512]
  const float* wvp = (const float*)d_in[5];    // [512,512]
  const float* wv2t = (const float*)d_in[6];   // [512,512]
  const float* dwk = (const float*)d_in[7];    // [512,1,3]
  const float* pwk = (const float*)d_in[8];    // [512,512,1]
  const float* lng = (const float*)d_in[9];    // [512]
  const float* lnb = (const float*)d_in[10];   // [512]
  const float* alpha = (const float*)d_in[11]; // scalar

  float* out_cls = (float*)d_out;                // [8192,1024]
  float* out_H = out_cls + (size_t)8192 * 1024;  // [8192,512]
  float* out_A = out_H + (size_t)8192 * 512;     // [8192,1024]

  // workspace layout
  char* p = (char*)d_ws;
  u16* KVb  = (u16*)p;              p += (size_t)32768 * 1024 * 2;
  u16* embb = (u16*)p;              p += (size_t)1024 * 512 * 2;
  u16* wqb  = (u16*)p;              p += (size_t)512 * 512 * 2;
  u16* wkvb = (u16*)p;              p += (size_t)1024 * 512 * 2;
  u16* wv2tb= (u16*)p;              p += (size_t)512 * 512 * 2;
  u16* pwkb = (u16*)p;              p += (size_t)512 * 512 * 2;
  u16* shmb = (u16*)p;              p += (size_t)8192 * 512 * 2;
  float* mbuf = (float*)p;          p += (size_t)8192 * 512 * 4;
  u16* qbuf = (u16*)p;              p += (size_t)8192 * 512 * 2;
  u16* Qbf  = (u16*)p;              p += (size_t)8192 * 512 * 2;
  u16* Fvb  = (u16*)p;              p += (size_t)8192 * 512 * 2;
  u16* Hb   = (u16*)p;              p += (size_t)8192 * 512 * 2;

  // small weights -> bf16
  cvt_weights<<<1792, 256, 0, stream>>>(emb, wq, wk, wvp, wv2t, pwk,
                                        embb, wqb, wkvb, wv2tb, pwkb);

  // KV = vis_f32 @ [wk;wv]^T  -> bf16 [32768][1024]  (fused convert)
  gemm_kv_f32a<<<dim3(8, 256), 256, 0, stream>>>(
      vis, wkvb, KVb, 32768, 1024, 512);

  // text front: gather + dwconv + silu + means
  text_front<<<8192, 256, 0, stream>>>(ids, emb, dwk, shmb, mbuf);
  // m += shm_mean @ pw^T  (pointwise conv folded through mean)
  gemm_n64<true, true, false><<<dim3(8, 64), 256, 0, stream>>>(
      shmb, pwkb, mbuf, nullptr, 8192, 512, 512);
  // LayerNorm -> q_txt (bf16)
  ln_kernel<<<8192, 256, 0, stream>>>(mbuf, lng, lnb, qbuf);
  // Q = q_txt @ wq^T (bf16 out)
  gemm_n64<false, false, true><<<dim3(8, 64), 256, 0, stream>>>(
      qbuf, wqb, nullptr, Qbf, 8192, 512, 512);
  // banded attention (MFMA) -> A (full rows, f32), Fv (bf16)
  attn_kernel<<<512, 512, 0, stream>>>(Qbf, KVb, alpha, out_A, Fvb);
  // H = Fv @ wv2t^T (f32 out + bf16 copy)
  gemm_n64<false, true, true><<<dim3(8, 64), 256, 0, stream>>>(
      Fvb, wv2tb, out_H, Hb, 8192, 512, 512);
  // cls = H @ emb^T (f32 out)
  gemm_mfma<false, true, false><<<dim3(8, 64), 256, 0, stream>>>(
      Hb, embb, out_cls, nullptr, 8192, 1024, 512);
}

// Round 9
// 220.457 us; speedup vs baseline: 1.0168x; 1.0168x over previous
//
#include <hip/hip_runtime.h>
#include <cmath>

typedef unsigned short u16;
typedef __attribute__((ext_vector_type(8))) short bf16x8;
typedef __attribute__((ext_vector_type(4))) float f32x4;
typedef __attribute__((ext_vector_type(8))) unsigned short u16x8;

#define B_  32
#define N_  1024
#define L_  256
#define S_  8
#define DT_ 512
#define BAND_ 16

__device__ __forceinline__ u16 f2bf(float f) {
  union { float f; unsigned u; } x; x.f = f;
  unsigned r = (x.u + 0x7fffu + ((x.u >> 16) & 1u)) >> 16;
  return (u16)r;
}
__device__ __forceinline__ float bf2f(u16 h) {
  union { unsigned u; float f; } x; x.u = ((unsigned)h) << 16;
  return x.f;
}
// packed f32x2 -> bf16x2 (RNE), 1 instr
__device__ __forceinline__ unsigned cvtpk(float lo, float hi) {
  unsigned r;
  asm volatile("v_cvt_pk_bf16_f32 %0, %1, %2" : "=v"(r) : "v"(lo), "v"(hi));
  return r;
}
// 8 f32 (two f32x4) -> bf16x8
__device__ __forceinline__ bf16x8 cvt8(f32x4 a, f32x4 b) {
  union { unsigned u[4]; bf16x8 h; } r;
  r.u[0] = cvtpk(a[0], a[1]); r.u[1] = cvtpk(a[2], a[3]);
  r.u[2] = cvtpk(b[0], b[1]); r.u[3] = cvtpk(b[2], b[3]);
  return r.h;
}

// ---------------------------------------------------------------------------
// All small weights in one launch. float4 counts:
// emb 131072 | wq 65536 | wk 65536 | wv 65536 | wv2t 65536 | pwk 65536
// ---------------------------------------------------------------------------
__global__ __launch_bounds__(256) void cvt_weights(
    const float* __restrict__ e, const float* __restrict__ q,
    const float* __restrict__ k, const float* __restrict__ v,
    const float* __restrict__ t, const float* __restrict__ pw,
    u16* __restrict__ eo, u16* __restrict__ qo, u16* __restrict__ kvo,
    u16* __restrict__ to, u16* __restrict__ po) {
  int i = blockIdx.x * 256 + threadIdx.x;
  const float* src; u16* dst; int soff, doff;
  if (i < 131072)      { src = e;  dst = eo;  soff = i;          doff = soff; }
  else if (i < 196608) { src = q;  dst = qo;  soff = i - 131072; doff = soff; }
  else if (i < 262144) { src = k;  dst = kvo; soff = i - 196608; doff = soff; }
  else if (i < 327680) { src = v;  dst = kvo; soff = i - 262144; doff = soff + 65536; }
  else if (i < 393216) { src = t;  dst = to;  soff = i - 327680; doff = soff; }
  else                 { src = pw; dst = po;  soff = i - 393216; doff = soff; }
  float4 vv = ((const float4*)src)[soff];
  ushort4 o;
  o.x = f2bf(vv.x); o.y = f2bf(vv.y); o.z = f2bf(vv.z); o.w = f2bf(vv.w);
  ((ushort4*)dst)[doff] = o;
}

// ---------------------------------------------------------------------------
// K1: per (b,l): gather emb rows, depthwise conv (k=3, SAME, cross-corr),
// silu, mean over s -> shm (bf16); meanE -> mbuf (f32)
// ---------------------------------------------------------------------------
__global__ __launch_bounds__(256) void text_front(
    const int* __restrict__ ids, const float* __restrict__ emb,
    const float* __restrict__ dwk, u16* __restrict__ shm,
    float* __restrict__ mbuf) {
  int bl = blockIdx.x;
  int tid = threadIdx.x;
  __shared__ int sid[S_];
  if (tid < S_) sid[tid] = ids[bl * S_ + tid];
  __syncthreads();
  for (int c = tid; c < DT_; c += 256) {
    float x[S_];
#pragma unroll
    for (int s = 0; s < S_; ++s) x[s] = emb[(size_t)sid[s] * DT_ + c];
    float k0 = dwk[c * 3 + 0], k1 = dwk[c * 3 + 1], k2 = dwk[c * 3 + 2];
    float me = 0.f, sh = 0.f;
#pragma unroll
    for (int s = 0; s < S_; ++s) {
      float xm = (s > 0) ? x[s - 1] : 0.0f;
      float xp = (s < S_ - 1) ? x[s + 1] : 0.0f;
      float h = k0 * xm + k1 * x[s] + k2 * xp;
      float si = h / (1.0f + expf(-h));  // silu
      me += x[s];
      sh += si;
    }
    shm[(size_t)bl * DT_ + c] = f2bf(sh * (1.0f / S_));
    mbuf[(size_t)bl * DT_ + c] = me * (1.0f / S_);
  }
}

// ---------------------------------------------------------------------------
// KV GEMM, fused f32->bf16 on A via LDS-f32 staging:
// C_bf16[m][n] = sum_k A_f32[m][k]*B_bf16[n][k].
// A staged f32 via global_load_lds with chunk-XOR swizzle on the GLOBAL
// source (LDS dest linear); frag reads apply the matching XOR -> bank-floor.
// Convert to bf16 at frag-read time (cvt_pk). B staged bf16 linear (as r7).
// Tile 128x128, BK=32, 256 thr. LDS: A 2x16KB f32 + B 2x8KB = 48KB.
// ---------------------------------------------------------------------------
__global__ __launch_bounds__(256) void gemm_kv_f32a(
    const float* __restrict__ A, const u16* __restrict__ B,
    u16* __restrict__ Cb, int M, int N, int K) {
  __shared__ float As[8192];  // [2][128][32] f32, chunk-swizzled
  __shared__ u16 Bs[8192];    // [2][128][32] bf16 linear
  const int tid = threadIdx.x;
  const int w = tid >> 6;
  const int lane = tid & 63;

  const int gx = gridDim.x;
  const int bid = blockIdx.y * gx + blockIdx.x;
  const int nwg = gx * gridDim.y;
  const int logical = (bid & 7) * (nwg >> 3) + (bid >> 3);
  const int bm = (logical / gx) << 7;
  const int bn = (logical % gx) << 7;
  const int wr = w >> 1, wc = w & 1;

  // A staging: wave w, load i covers rows w*32+i*8+(lane>>3), 16B chunk lane&7.
  // Global source chunk = (lane&7) ^ (row&7)  [row&7 = (lane>>3)&7]
  const int ar0 = (w << 5) + (lane >> 3);
  const int ac = (((lane & 7) ^ ((lane >> 3) & 7)) << 2);  // f32 col
  const float* Ag = A + (size_t)(bm + ar0) * K + ac;

  // B staging (bf16 linear): wave w rows w*16+(lane>>2), k-chunk (lane&3)*8
  const int r0 = (w << 4) + (lane >> 2);
  const int kc = (lane & 3) << 3;
  const u16* Bg0 = B + (size_t)(bn + r0) * K + kc;
  const u16* Bg1 = Bg0 + (size_t)64 * K;

  // A frag read offsets (f32 idx): row*32 + ((2*kg+c)^(lane&7))*4
  int afo[4][2];
#pragma unroll
  for (int m = 0; m < 4; ++m) {
    const int row = (wr << 6) + (m << 4) + (lane & 15);
#pragma unroll
    for (int c = 0; c < 2; ++c)
      afo[m][c] = (row << 5) + ((((lane >> 4) * 2 + c) ^ (lane & 7)) << 2);
  }
  // B frag read offsets (u16 idx, linear)
  int boff[4];
#pragma unroll
  for (int n = 0; n < 4; ++n)
    boff[n] = (((wc << 6) + (n << 4) + (lane & 15)) << 5) + ((lane >> 4) << 3);

  f32x4 acc[4][4];
#pragma unroll
  for (int m = 0; m < 4; ++m)
#pragma unroll
    for (int n = 0; n < 4; ++n) acc[m][n] = (f32x4){0.f, 0.f, 0.f, 0.f};

#define STAGE(buf, kt)                                                        \
  {                                                                           \
    float* asb = As + (buf) * 4096 + ((w << 5) << 5);                         \
    _Pragma("unroll")                                                         \
    for (int i = 0; i < 4; ++i) {                                             \
      __builtin_amdgcn_global_load_lds(                                       \
          (const __attribute__((address_space(1))) void*)(Ag + (size_t)(i * 8) * K + (kt)), \
          (__attribute__((address_space(3))) void*)(asb + (i << 8)), 16, 0, 0); \
    }                                                                         \
    u16* bs_ = Bs + (buf) * 4096 + (w << 9);                                  \
    __builtin_amdgcn_global_load_lds(                                         \
        (const __attribute__((address_space(1))) void*)(Bg0 + (kt)),          \
        (__attribute__((address_space(3))) void*)bs_, 16, 0, 0);              \
    __builtin_amdgcn_global_load_lds(                                         \
        (const __attribute__((address_space(1))) void*)(Bg1 + (kt)),          \
        (__attribute__((address_space(3))) void*)(bs_ + 2048), 16, 0, 0);     \
  }

  const int nt = K >> 5;
  STAGE(0, 0);
  __syncthreads();
  int cur = 0;
  for (int t = 0; t < nt; ++t) {
    if (t + 1 < nt) STAGE(cur ^ 1, (t + 1) << 5);
    const float* Ab = As + cur * 4096;
    const u16* Bb = Bs + cur * 4096;
    bf16x8 af[4], bfr[4];
#pragma unroll
    for (int m = 0; m < 4; ++m) {
      f32x4 a0 = *(const f32x4*)(Ab + afo[m][0]);
      f32x4 a1 = *(const f32x4*)(Ab + afo[m][1]);
      af[m] = cvt8(a0, a1);
    }
#pragma unroll
    for (int n = 0; n < 4; ++n) bfr[n] = *(const bf16x8*)(Bb + boff[n]);
#pragma unroll
    for (int m = 0; m < 4; ++m)
#pragma unroll
      for (int n = 0; n < 4; ++n)
        acc[m][n] = __builtin_amdgcn_mfma_f32_16x16x32_bf16(
            af[m], bfr[n], acc[m][n], 0, 0, 0);
    __syncthreads();
    cur ^= 1;
  }
#undef STAGE

  const int rb = bm + (wr << 6) + ((lane >> 4) << 2);
  const int cb = bn + (wc << 6) + (lane & 15);
#pragma unroll
  for (int m = 0; m < 4; ++m)
#pragma unroll
    for (int n = 0; n < 4; ++n) {
      int col = cb + (n << 4);
#pragma unroll
      for (int j = 0; j < 4; ++j) {
        size_t idx = (size_t)(rb + (m << 4) + j) * N + col;
        Cb[idx] = f2bf(acc[m][n][j]);
      }
    }
}

// ---------------------------------------------------------------------------
// bf16 MFMA GEMM, 128x128 tile (used for cls). 2-phase + XCD swizzle.
// ---------------------------------------------------------------------------
template <bool ACC, bool WF32, bool WBF16>
__global__ __launch_bounds__(256) void gemm_mfma(
    const u16* __restrict__ A, const u16* __restrict__ B,
    float* __restrict__ C, u16* __restrict__ Cb, int M, int N, int K) {
  __shared__ u16 As[8192];
  __shared__ u16 Bs[8192];
  const int tid = threadIdx.x;
  const int w = tid >> 6;
  const int lane = tid & 63;

  const int gx = gridDim.x;
  const int bid = blockIdx.y * gx + blockIdx.x;
  const int nwg = gx * gridDim.y;
  const int logical = (bid & 7) * (nwg >> 3) + (bid >> 3);
  const int bm = (logical / gx) << 7;
  const int bn = (logical % gx) << 7;
  const int wr = w >> 1, wc = w & 1;

  const int r0 = (w << 4) + (lane >> 2);
  const int kc = (lane & 3) << 3;
  const u16* Ag0 = A + (size_t)(bm + r0) * K + kc;
  const u16* Ag1 = Ag0 + (size_t)64 * K;
  const u16* Bg0 = B + (size_t)(bn + r0) * K + kc;
  const u16* Bg1 = Bg0 + (size_t)64 * K;

  int aoff[4], boff[4];
#pragma unroll
  for (int m = 0; m < 4; ++m)
    aoff[m] = (((wr << 6) + (m << 4) + (lane & 15)) << 5) + ((lane >> 4) << 3);
#pragma unroll
  for (int n = 0; n < 4; ++n)
    boff[n] = (((wc << 6) + (n << 4) + (lane & 15)) << 5) + ((lane >> 4) << 3);

  f32x4 acc[4][4];
#pragma unroll
  for (int m = 0; m < 4; ++m)
#pragma unroll
    for (int n = 0; n < 4; ++n) acc[m][n] = (f32x4){0.f, 0.f, 0.f, 0.f};

#define STAGE(buf, kt)                                                        \
  {                                                                           \
    u16* as_ = As + (buf) * 4096 + (w << 9);                                  \
    u16* bs_ = Bs + (buf) * 4096 + (w << 9);                                  \
    __builtin_amdgcn_global_load_lds(                                         \
        (const __attribute__((address_space(1))) void*)(Ag0 + (kt)),          \
        (__attribute__((address_space(3))) void*)as_, 16, 0, 0);              \
    __builtin_amdgcn_global_load_lds(                                         \
        (const __attribute__((address_space(1))) void*)(Ag1 + (kt)),          \
        (__attribute__((address_space(3))) void*)(as_ + 2048), 16, 0, 0);     \
    __builtin_amdgcn_global_load_lds(                                         \
        (const __attribute__((address_space(1))) void*)(Bg0 + (kt)),          \
        (__attribute__((address_space(3))) void*)bs_, 16, 0, 0);              \
    __builtin_amdgcn_global_load_lds(                                         \
        (const __attribute__((address_space(1))) void*)(Bg1 + (kt)),          \
        (__attribute__((address_space(3))) void*)(bs_ + 2048), 16, 0, 0);     \
  }

  const int nt = K >> 5;
  STAGE(0, 0);
  __syncthreads();
  int cur = 0;
  for (int t = 0; t < nt; ++t) {
    if (t + 1 < nt) STAGE(cur ^ 1, (t + 1) << 5);
    const u16* Ab = As + cur * 4096;
    const u16* Bb = Bs + cur * 4096;
    bf16x8 af[4], bfr[4];
#pragma unroll
    for (int m = 0; m < 4; ++m) af[m] = *(const bf16x8*)(Ab + aoff[m]);
#pragma unroll
    for (int n = 0; n < 4; ++n) bfr[n] = *(const bf16x8*)(Bb + boff[n]);
#pragma unroll
    for (int m = 0; m < 4; ++m)
#pragma unroll
      for (int n = 0; n < 4; ++n)
        acc[m][n] = __builtin_amdgcn_mfma_f32_16x16x32_bf16(
            af[m], bfr[n], acc[m][n], 0, 0, 0);
    __syncthreads();
    cur ^= 1;
  }
#undef STAGE

  const int rb = bm + (wr << 6) + ((lane >> 4) << 2);
  const int cb = bn + (wc << 6) + (lane & 15);
#pragma unroll
  for (int m = 0; m < 4; ++m)
#pragma unroll
    for (int n = 0; n < 4; ++n) {
      int col = cb + (n << 4);
#pragma unroll
      for (int j = 0; j < 4; ++j) {
        size_t idx = (size_t)(rb + (m << 4) + j) * N + col;
        float v = acc[m][n][j];
        if (ACC) v += C[idx];
        if (WF32) C[idx] = v;
        if (WBF16) Cb[idx] = f2bf(v);
      }
    }
}

// ---------------------------------------------------------------------------
// bf16 MFMA GEMM, 128x64 tile for N=512 GEMMs (512 blocks -> 2/CU).
// ---------------------------------------------------------------------------
template <bool ACC, bool WF32, bool WBF16>
__global__ __launch_bounds__(256) void gemm_n64(
    const u16* __restrict__ A, const u16* __restrict__ B,
    float* __restrict__ C, u16* __restrict__ Cb, int M, int N, int K) {
  __shared__ u16 As[8192];  // [2][128][32]
  __shared__ u16 Bs[4096];  // [2][64][32]
  const int tid = threadIdx.x;
  const int w = tid >> 6;
  const int lane = tid & 63;

  const int gx = gridDim.x;  // N/64
  const int bid = blockIdx.y * gx + blockIdx.x;
  const int nwg = gx * gridDim.y;
  const int logical = (bid & 7) * (nwg >> 3) + (bid >> 3);
  const int bm = (logical / gx) << 7;
  const int bn = (logical % gx) << 6;

  const int r0 = (w << 4) + (lane >> 2);
  const int kc = (lane & 3) << 3;
  const u16* Ag0 = A + (size_t)(bm + r0) * K + kc;
  const u16* Ag1 = Ag0 + (size_t)64 * K;
  const u16* Bg0 = B + (size_t)(bn + r0) * K + kc;

  int aoff[2], boff[4];
#pragma unroll
  for (int m = 0; m < 2; ++m)
    aoff[m] = (((w << 5) + (m << 4) + (lane & 15)) << 5) + ((lane >> 4) << 3);
#pragma unroll
  for (int n = 0; n < 4; ++n)
    boff[n] = (((n << 4) + (lane & 15)) << 5) + ((lane >> 4) << 3);

  f32x4 acc[2][4];
#pragma unroll
  for (int m = 0; m < 2; ++m)
#pragma unroll
    for (int n = 0; n < 4; ++n) acc[m][n] = (f32x4){0.f, 0.f, 0.f, 0.f};

#define STAGE(buf, kt)                                                        \
  {                                                                           \
    u16* as_ = As + (buf) * 4096 + (w << 9);                                  \
    u16* bs_ = Bs + (buf) * 2048 + (w << 9);                                  \
    __builtin_amdgcn_global_load_lds(                                         \
        (const __attribute__((address_space(1))) void*)(Ag0 + (kt)),          \
        (__attribute__((address_space(3))) void*)as_, 16, 0, 0);              \
    __builtin_amdgcn_global_load_lds(                                         \
        (const __attribute__((address_space(1))) void*)(Ag1 + (kt)),          \
        (__attribute__((address_space(3))) void*)(as_ + 2048), 16, 0, 0);     \
    __builtin_amdgcn_global_load_lds(                                         \
        (const __attribute__((address_space(1))) void*)(Bg0 + (kt)),          \
        (__attribute__((address_space(3))) void*)bs_, 16, 0, 0);              \
  }

  const int nt = K >> 5;
  STAGE(0, 0);
  __syncthreads();
  int cur = 0;
  for (int t = 0; t < nt; ++t) {
    if (t + 1 < nt) STAGE(cur ^ 1, (t + 1) << 5);
    const u16* Ab = As + cur * 4096;
    const u16* Bb = Bs + cur * 2048;
    bf16x8 af[2], bfr[4];
#pragma unroll
    for (int m = 0; m < 2; ++m) af[m] = *(const bf16x8*)(Ab + aoff[m]);
#pragma unroll
    for (int n = 0; n < 4; ++n) bfr[n] = *(const bf16x8*)(Bb + boff[n]);
#pragma unroll
    for (int m = 0; m < 2; ++m)
#pragma unroll
      for (int n = 0; n < 4; ++n)
        acc[m][n] = __builtin_amdgcn_mfma_f32_16x16x32_bf16(
            af[m], bfr[n], acc[m][n], 0, 0, 0);
    __syncthreads();
    cur ^= 1;
  }
#undef STAGE

  const int rb = bm + (w << 5) + ((lane >> 4) << 2);
  const int cb = bn + (lane & 15);
#pragma unroll
  for (int m = 0; m < 2; ++m)
#pragma unroll
    for (int n = 0; n < 4; ++n) {
      int col = cb + (n << 4);
#pragma unroll
      for (int j = 0; j < 4; ++j) {
        size_t idx = (size_t)(rb + (m << 4) + j) * N + col;
        float v = acc[m][n][j];
        if (ACC) v += C[idx];
        if (WF32) C[idx] = v;
        if (WBF16) Cb[idx] = f2bf(v);
      }
    }
}

// ---------------------------------------------------------------------------
// LayerNorm over DT=512 per row; writes bf16 q_txt
// ---------------------------------------------------------------------------
__global__ __launch_bounds__(256) void ln_kernel(
    const float* __restrict__ m, const float* __restrict__ g,
    const float* __restrict__ bta, u16* __restrict__ q) {
  int row = blockIdx.x;
  int tid = threadIdx.x;
  float v0 = m[(size_t)row * 512 + tid];
  float v1 = m[(size_t)row * 512 + 256 + tid];
  __shared__ float red[4], red2[4];
  float s = v0 + v1;
#pragma unroll
  for (int d = 32; d; d >>= 1) s += __shfl_xor(s, d);
  if ((tid & 63) == 0) red[tid >> 6] = s;
  __syncthreads();
  float mu = (red[0] + red[1] + red[2] + red[3]) * (1.0f / 512.0f);
  float d0 = v0 - mu, d1 = v1 - mu;
  float s2 = d0 * d0 + d1 * d1;
#pragma unroll
  for (int d = 32; d; d >>= 1) s2 += __shfl_xor(s2, d);
  if ((tid & 63) == 0) red2[tid >> 6] = s2;
  __syncthreads();
  float var = (red2[0] + red2[1] + red2[2] + red2[3]) * (1.0f / 512.0f);
  float r = rsqrtf(var + 1e-5f);
  q[(size_t)row * 512 + tid] = f2bf(d0 * r * g[tid] + bta[tid]);
  q[(size_t)row * 512 + 256 + tid] = f2bf(d1 * r * g[tid + 256] + bta[tid + 256]);
}

// ---------------------------------------------------------------------------
// MFMA banded attention. Block = (b, 16 l), 512 threads = 8 waves.
// ---------------------------------------------------------------------------
__global__ __launch_bounds__(512) void attn_kernel(
    const u16* __restrict__ Qb, const u16* __restrict__ KV,
    const float* __restrict__ alpha_p, float* __restrict__ A,
    u16* __restrict__ Fv) {
  __shared__ u16 KV_s[96 * 512];   // 96 KB, K then reused for V
  __shared__ u16 Q_s[16 * 520];    // padded stride 520 u16
  __shared__ float S_s[16 * 100];  // logits then attention weights

  const int bid = blockIdx.x;
  const int logical = (bid & 7) * 64 + (bid >> 3);
  const int b = logical >> 4, lg = logical & 15;
  const int l0 = lg * 16;
  const int tid = threadIdx.x;
  const int w = tid >> 6, lane = tid & 63;
  const float al = *alpha_p;

  const int c_min = (1023 * l0) / 255;
  const int kb0 = min(max(c_min - BAND_, 0), N_ - 96);

  {
    const size_t rowb = (size_t)(b * N_ + kb0);
    for (int rr = 0; rr < 12; ++rr) {
      const int r = w * 12 + rr;
      const u16* src = KV + (rowb + r) * 1024 + ((lane * 8) ^ ((r & 7) << 3));
      u16* dst = KV_s + r * 512;
      __builtin_amdgcn_global_load_lds(
          (const __attribute__((address_space(1))) void*)src,
          (__attribute__((address_space(3))) void*)dst, 16, 0, 0);
    }
  }
  {
    const int r = tid >> 5;
    const u16* qrow = Qb + (size_t)(b * L_ + l0 + r) * 512;
#pragma unroll
    for (int h = 0; h < 2; ++h) {
      const int ch = (tid & 31) + h * 32;
      u16x8 v = *(const u16x8*)(qrow + ch * 8);
      *(u16x8*)(Q_s + r * 520 + ch * 8) = v;
    }
  }
  __syncthreads();

  if (w < 6) {
    f32x4 acc = {0.f, 0.f, 0.f, 0.f};
    const int arow = (lane & 15) * 520 + ((lane >> 4) << 3);
    const int key = w * 16 + (lane & 15);
    const int swz = (key & 7) << 3;
    for (int ks = 0; ks < 16; ++ks) {
      bf16x8 aq = *(const bf16x8*)(Q_s + arow + ks * 32);
      bf16x8 bk =
          *(const bf16x8*)(KV_s + key * 512 + ((ks * 32 + ((lane >> 4) << 3)) ^ swz));
      acc = __builtin_amdgcn_mfma_f32_16x16x32_bf16(aq, bk, acc, 0, 0, 0);
    }
#pragma unroll
    for (int j = 0; j < 4; ++j)
      S_s[((lane >> 4) * 4 + j) * 100 + w * 16 + (lane & 15)] = acc[j];
  }
  __syncthreads();

  {
    const size_t rowb = (size_t)(b * N_ + kb0);
    for (int rr = 0; rr < 12; ++rr) {
      const int r = w * 12 + rr;
      const u16* src =
          KV + (rowb + r) * 1024 + 512 + ((lane * 8) ^ ((r & 7) << 3));
      u16* dst = KV_s + r * 512;
      __builtin_amdgcn_global_load_lds(
          (const __attribute__((address_space(1))) void*)src,
          (__attribute__((address_space(3))) void*)dst, 16, 0, 0);
    }
  }

#pragma unroll
  for (int rr = 0; rr < 2; ++rr) {
    const int l = 2 * w + rr;
    const int c = (1023 * (l0 + l)) / 255;
    const int g0 = kb0 + lane, g1 = kb0 + 64 + lane;
    const bool v0 = (g0 >= c - BAND_) && (g0 <= c + BAND_);
    const bool v1 = (lane < 32) && (g1 >= c - BAND_) && (g1 <= c + BAND_);
    const float sc = 0.044194173824159216f;
    float x0 = v0 ? S_s[l * 100 + lane] * sc +
                        al * ((float)(c - g0) * (1.0f / 16.000001f))
                  : -INFINITY;
    float x1 = v1 ? S_s[l * 100 + 64 + lane] * sc +
                        al * ((float)(c - g1) * (1.0f / 16.000001f))
                  : -INFINITY;
    float mx = fmaxf(x0, x1);
#pragma unroll
    for (int d = 32; d; d >>= 1) mx = fmaxf(mx, __shfl_xor(mx, d));
    float e0 = v0 ? expf(x0 - mx) : 0.0f;
    float e1 = v1 ? expf(x1 - mx) : 0.0f;
    float sm = e0 + e1;
#pragma unroll
    for (int d = 32; d; d >>= 1) sm += __shfl_xor(sm, d);
    const float inv = 1.0f / sm;
    S_s[l * 100 + lane] = e0 * inv;
    if (lane < 32) S_s[l * 100 + 64 + lane] = e1 * inv;
    const int lo = max(0, c - BAND_), hi = min(N_ - 1, c + BAND_);
    float* Arow = A + (size_t)(b * L_ + l0 + l) * N_;
#pragma unroll
    for (int p4 = 0; p4 < 4; ++p4) {
      const int p = (p4 * 64 + lane) * 4;
      float4 v;
      v.x = (p + 0 >= lo && p + 0 <= hi) ? S_s[l * 100 + p + 0 - kb0] : 0.0f;
      v.y = (p + 1 >= lo && p + 1 <= hi) ? S_s[l * 100 + p + 1 - kb0] : 0.0f;
      v.z = (p + 2 >= lo && p + 2 <= hi) ? S_s[l * 100 + p + 2 - kb0] : 0.0f;
      v.w = (p + 3 >= lo && p + 3 <= hi) ? S_s[l * 100 + p + 3 - kb0] : 0.0f;
      ((float4*)Arow)[p4 * 64 + lane] = v;
    }
  }
  __syncthreads();

#pragma unroll
  for (int rr = 0; rr < 2; ++rr) {
    const int l = 2 * w + rr;
    const int c = (1023 * (l0 + l)) / 255;
    const int jlo = max(0, c - BAND_) - kb0, jhi = min(N_ - 1, c + BAND_) - kb0;
    float acc[8] = {};
    for (int j = jlo; j <= jhi; ++j) {
      const float avj = S_s[l * 100 + j];
      const u16x8 v =
          *(const u16x8*)(KV_s + j * 512 + ((lane * 8) ^ ((j & 7) << 3)));
#pragma unroll
      for (int t = 0; t < 8; ++t) acc[t] += avj * bf2f(v[t]);
    }
    u16x8 fo;
#pragma unroll
    for (int t = 0; t < 8; ++t) fo[t] = f2bf(acc[t]);
    *(u16x8*)(Fv + (size_t)(b * L_ + l0 + l) * 512 + lane * 8) = fo;
  }
}

// ---------------------------------------------------------------------------
extern "C" void kernel_launch(void* const* d_in, const int* in_sizes, int n_in,
                              void* d_out, int out_size, void* d_ws,
                              size_t ws_size, hipStream_t stream) {
  const float* vis = (const float*)d_in[0];    // [32,1024,512]
  const int* ids = (const int*)d_in[1];        // [32,256,8]
  const float* emb = (const float*)d_in[2];    // [1024,512]
  const float* wq = (const float*)d_in[3];     // [512,512]
  const float* wk = (const float*)d_in[4];     // [512,512]
  const float* wvp = (const float*)d_in[5];    // [512,512]
  const float* wv2t = (const float*)d_in[6];   // [512,512]
  const float* dwk = (const float*)d_in[7];    // [512,1,3]
  const float* pwk = (const float*)d_in[8];    // [512,512,1]
  const float* lng = (const float*)d_in[9];    // [512]
  const float* lnb = (const float*)d_in[10];   // [512]
  const float* alpha = (const float*)d_in[11]; // scalar

  float* out_cls = (float*)d_out;                // [8192,1024]
  float* out_H = out_cls + (size_t)8192 * 1024;  // [8192,512]
  float* out_A = out_H + (size_t)8192 * 512;     // [8192,1024]

  // workspace layout
  char* p = (char*)d_ws;
  u16* KVb  = (u16*)p;              p += (size_t)32768 * 1024 * 2;
  u16* embb = (u16*)p;              p += (size_t)1024 * 512 * 2;
  u16* wqb  = (u16*)p;              p += (size_t)512 * 512 * 2;
  u16* wkvb = (u16*)p;              p += (size_t)1024 * 512 * 2;
  u16* wv2tb= (u16*)p;              p += (size_t)512 * 512 * 2;
  u16* pwkb = (u16*)p;              p += (size_t)512 * 512 * 2;
  u16* shmb = (u16*)p;              p += (size_t)8192 * 512 * 2;
  float* mbuf = (float*)p;          p += (size_t)8192 * 512 * 4;
  u16* qbuf = (u16*)p;              p += (size_t)8192 * 512 * 2;
  u16* Qbf  = (u16*)p;              p += (size_t)8192 * 512 * 2;
  u16* Fvb  = (u16*)p;              p += (size_t)8192 * 512 * 2;
  u16* Hb   = (u16*)p;              p += (size_t)8192 * 512 * 2;

  // small weights -> bf16
  cvt_weights<<<1792, 256, 0, stream>>>(emb, wq, wk, wvp, wv2t, pwk,
                                        embb, wqb, wkvb, wv2tb, pwkb);

  // KV = vis_f32 @ [wk;wv]^T  -> bf16 [32768][1024]  (fused convert, LDS-f32)
  gemm_kv_f32a<<<dim3(8, 256), 256, 0, stream>>>(
      vis, wkvb, KVb, 32768, 1024, 512);

  // text front: gather + dwconv + silu + means
  text_front<<<8192, 256, 0, stream>>>(ids, emb, dwk, shmb, mbuf);
  // m += shm_mean @ pw^T  (pointwise conv folded through mean)
  gemm_n64<true, true, false><<<dim3(8, 64), 256, 0, stream>>>(
      shmb, pwkb, mbuf, nullptr, 8192, 512, 512);
  // LayerNorm -> q_txt (bf16)
  ln_kernel<<<8192, 256, 0, stream>>>(mbuf, lng, lnb, qbuf);
  // Q = q_txt @ wq^T (bf16 out)
  gemm_n64<false, false, true><<<dim3(8, 64), 256, 0, stream>>>(
      qbuf, wqb, nullptr, Qbf, 8192, 512, 512);
  // banded attention (MFMA) -> A (full rows, f32), Fv (bf16)
  attn_kernel<<<512, 512, 0, stream>>>(Qbf, KVb, alpha, out_A, Fvb);
  // H = Fv @ wv2t^T (f32 out + bf16 copy)
  gemm_n64<false, true, true><<<dim3(8, 64), 256, 0, stream>>>(
      Fvb, wv2tb, out_H, Hb, 8192, 512, 512);
  // cls = H @ emb^T (f32 out)
  gemm_mfma<false, true, false><<<dim3(8, 64), 256, 0, stream>>>(
      Hb, embb, out_cls, nullptr, 8192, 1024, 512);
}

// Round 10
// 219.449 us; speedup vs baseline: 1.0215x; 1.0046x over previous
//
#include <hip/hip_runtime.h>
#include <cmath>

typedef unsigned short u16;
typedef __attribute__((ext_vector_type(8))) short bf16x8;
typedef __attribute__((ext_vector_type(4))) float f32x4;
typedef __attribute__((ext_vector_type(8))) unsigned short u16x8;

#define B_  32
#define N_  1024
#define L_  256
#define S_  8
#define DT_ 512
#define BAND_ 16

__device__ __forceinline__ u16 f2bf(float f) {
  union { float f; unsigned u; } x; x.f = f;
  unsigned r = (x.u + 0x7fffu + ((x.u >> 16) & 1u)) >> 16;
  return (u16)r;
}
__device__ __forceinline__ float bf2f(u16 h) {
  union { unsigned u; float f; } x; x.u = ((unsigned)h) << 16;
  return x.f;
}
// packed f32x2 -> bf16x2 (RNE), 1 instr
__device__ __forceinline__ unsigned cvtpk(float lo, float hi) {
  unsigned r;
  asm volatile("v_cvt_pk_bf16_f32 %0, %1, %2" : "=v"(r) : "v"(lo), "v"(hi));
  return r;
}
// 8 f32 (two f32x4) -> bf16x8
__device__ __forceinline__ bf16x8 cvt8(f32x4 a, f32x4 b) {
  union { unsigned u[4]; bf16x8 h; } r;
  r.u[0] = cvtpk(a[0], a[1]); r.u[1] = cvtpk(a[2], a[3]);
  r.u[2] = cvtpk(b[0], b[1]); r.u[3] = cvtpk(b[2], b[3]);
  return r.h;
}

// counted-vmcnt barrier pair helpers (T4): tile t ready, prefetch stays in flight
#define B1_WAIT(N)                                       \
  asm volatile("s_waitcnt vmcnt(" #N ")" ::: "memory");  \
  __builtin_amdgcn_s_barrier();                          \
  __builtin_amdgcn_sched_barrier(0);
#define B2_BAR()                                         \
  __builtin_amdgcn_sched_barrier(0);                     \
  __builtin_amdgcn_s_barrier();

// ---------------------------------------------------------------------------
// All small weights in one launch.
// ---------------------------------------------------------------------------
__global__ __launch_bounds__(256) void cvt_weights(
    const float* __restrict__ e, const float* __restrict__ q,
    const float* __restrict__ k, const float* __restrict__ v,
    const float* __restrict__ t, const float* __restrict__ pw,
    u16* __restrict__ eo, u16* __restrict__ qo, u16* __restrict__ kvo,
    u16* __restrict__ to, u16* __restrict__ po) {
  int i = blockIdx.x * 256 + threadIdx.x;
  const float* src; u16* dst; int soff, doff;
  if (i < 131072)      { src = e;  dst = eo;  soff = i;          doff = soff; }
  else if (i < 196608) { src = q;  dst = qo;  soff = i - 131072; doff = soff; }
  else if (i < 262144) { src = k;  dst = kvo; soff = i - 196608; doff = soff; }
  else if (i < 327680) { src = v;  dst = kvo; soff = i - 262144; doff = soff + 65536; }
  else if (i < 393216) { src = t;  dst = to;  soff = i - 327680; doff = soff; }
  else                 { src = pw; dst = po;  soff = i - 393216; doff = soff; }
  float4 vv = ((const float4*)src)[soff];
  ushort4 o;
  o.x = f2bf(vv.x); o.y = f2bf(vv.y); o.z = f2bf(vv.z); o.w = f2bf(vv.w);
  ((ushort4*)dst)[doff] = o;
}

// ---------------------------------------------------------------------------
// K1: gather emb rows, depthwise conv, silu, means
// ---------------------------------------------------------------------------
__global__ __launch_bounds__(256) void text_front(
    const int* __restrict__ ids, const float* __restrict__ emb,
    const float* __restrict__ dwk, u16* __restrict__ shm,
    float* __restrict__ mbuf) {
  int bl = blockIdx.x;
  int tid = threadIdx.x;
  __shared__ int sid[S_];
  if (tid < S_) sid[tid] = ids[bl * S_ + tid];
  __syncthreads();
  for (int c = tid; c < DT_; c += 256) {
    float x[S_];
#pragma unroll
    for (int s = 0; s < S_; ++s) x[s] = emb[(size_t)sid[s] * DT_ + c];
    float k0 = dwk[c * 3 + 0], k1 = dwk[c * 3 + 1], k2 = dwk[c * 3 + 2];
    float me = 0.f, sh = 0.f;
#pragma unroll
    for (int s = 0; s < S_; ++s) {
      float xm = (s > 0) ? x[s - 1] : 0.0f;
      float xp = (s < S_ - 1) ? x[s + 1] : 0.0f;
      float h = k0 * xm + k1 * x[s] + k2 * xp;
      float si = h / (1.0f + expf(-h));  // silu
      me += x[s];
      sh += si;
    }
    shm[(size_t)bl * DT_ + c] = f2bf(sh * (1.0f / S_));
    mbuf[(size_t)bl * DT_ + c] = me * (1.0f / S_);
  }
}

// ---------------------------------------------------------------------------
// KV GEMM, fused f32->bf16 on A via LDS-f32 staging, counted-vmcnt pipeline.
// 6 gload_lds per wave per STAGE -> B1 waits vmcnt(6).
// ---------------------------------------------------------------------------
__global__ __launch_bounds__(256, 3) void gemm_kv_f32a(
    const float* __restrict__ A, const u16* __restrict__ B,
    u16* __restrict__ Cb, int M, int N, int K) {
  __shared__ float As[8192];  // [2][128][32] f32, chunk-swizzled
  __shared__ u16 Bs[8192];    // [2][128][32] bf16 linear
  const int tid = threadIdx.x;
  const int w = tid >> 6;
  const int lane = tid & 63;

  const int gx = gridDim.x;
  const int bid = blockIdx.y * gx + blockIdx.x;
  const int nwg = gx * gridDim.y;
  const int logical = (bid & 7) * (nwg >> 3) + (bid >> 3);
  const int bm = (logical / gx) << 7;
  const int bn = (logical % gx) << 7;
  const int wr = w >> 1, wc = w & 1;

  const int ar0 = (w << 5) + (lane >> 3);
  const int ac = (((lane & 7) ^ ((lane >> 3) & 7)) << 2);  // f32 col (src swz)
  const float* Ag = A + (size_t)(bm + ar0) * K + ac;

  const int r0 = (w << 4) + (lane >> 2);
  const int kc = (lane & 3) << 3;
  const u16* Bg0 = B + (size_t)(bn + r0) * K + kc;
  const u16* Bg1 = Bg0 + (size_t)64 * K;

  int afo[4][2];
#pragma unroll
  for (int m = 0; m < 4; ++m) {
    const int row = (wr << 6) + (m << 4) + (lane & 15);
#pragma unroll
    for (int c = 0; c < 2; ++c)
      afo[m][c] = (row << 5) + ((((lane >> 4) * 2 + c) ^ (lane & 7)) << 2);
  }
  int boff[4];
#pragma unroll
  for (int n = 0; n < 4; ++n)
    boff[n] = (((wc << 6) + (n << 4) + (lane & 15)) << 5) + ((lane >> 4) << 3);

  f32x4 acc[4][4];
#pragma unroll
  for (int m = 0; m < 4; ++m)
#pragma unroll
    for (int n = 0; n < 4; ++n) acc[m][n] = (f32x4){0.f, 0.f, 0.f, 0.f};

#define STAGE(buf, kt)                                                        \
  {                                                                           \
    float* asb = As + (buf) * 4096 + ((w << 5) << 5);                         \
    _Pragma("unroll")                                                         \
    for (int i = 0; i < 4; ++i) {                                             \
      __builtin_amdgcn_global_load_lds(                                       \
          (const __attribute__((address_space(1))) void*)(Ag + (size_t)(i * 8) * K + (kt)), \
          (__attribute__((address_space(3))) void*)(asb + (i << 8)), 16, 0, 0); \
    }                                                                         \
    u16* bs_ = Bs + (buf) * 4096 + (w << 9);                                  \
    __builtin_amdgcn_global_load_lds(                                         \
        (const __attribute__((address_space(1))) void*)(Bg0 + (kt)),          \
        (__attribute__((address_space(3))) void*)bs_, 16, 0, 0);              \
    __builtin_amdgcn_global_load_lds(                                         \
        (const __attribute__((address_space(1))) void*)(Bg1 + (kt)),          \
        (__attribute__((address_space(3))) void*)(bs_ + 2048), 16, 0, 0);     \
  }

  const int nt = K >> 5;
  STAGE(0, 0);
  int cur = 0;
  for (int t = 0; t < nt; ++t) {
    if (t + 1 < nt) {
      STAGE(cur ^ 1, (t + 1) << 5);
      B1_WAIT(6)   // tile t landed; tile t+1's 6 loads stay in flight
    } else {
      B1_WAIT(0)
    }
    const float* Ab = As + cur * 4096;
    const u16* Bb = Bs + cur * 4096;
    bf16x8 af[4], bfr[4];
#pragma unroll
    for (int m = 0; m < 4; ++m) {
      f32x4 a0 = *(const f32x4*)(Ab + afo[m][0]);
      f32x4 a1 = *(const f32x4*)(Ab + afo[m][1]);
      af[m] = cvt8(a0, a1);
    }
#pragma unroll
    for (int n = 0; n < 4; ++n) bfr[n] = *(const bf16x8*)(Bb + boff[n]);
#pragma unroll
    for (int m = 0; m < 4; ++m)
#pragma unroll
      for (int n = 0; n < 4; ++n)
        acc[m][n] = __builtin_amdgcn_mfma_f32_16x16x32_bf16(
            af[m], bfr[n], acc[m][n], 0, 0, 0);
    B2_BAR()  // all reads of cur done before anyone stages t+2 into it
    cur ^= 1;
  }
#undef STAGE

  const int rb = bm + (wr << 6) + ((lane >> 4) << 2);
  const int cb = bn + (wc << 6) + (lane & 15);
#pragma unroll
  for (int m = 0; m < 4; ++m)
#pragma unroll
    for (int n = 0; n < 4; ++n) {
      int col = cb + (n << 4);
#pragma unroll
      for (int j = 0; j < 4; ++j) {
        size_t idx = (size_t)(rb + (m << 4) + j) * N + col;
        Cb[idx] = f2bf(acc[m][n][j]);
      }
    }
}

// ---------------------------------------------------------------------------
// bf16 MFMA GEMM, 128x128 tile (cls), counted-vmcnt pipeline (4 loads/STAGE).
// ---------------------------------------------------------------------------
template <bool ACC, bool WF32, bool WBF16>
__global__ __launch_bounds__(256) void gemm_mfma(
    const u16* __restrict__ A, const u16* __restrict__ B,
    float* __restrict__ C, u16* __restrict__ Cb, int M, int N, int K) {
  __shared__ u16 As[8192];
  __shared__ u16 Bs[8192];
  const int tid = threadIdx.x;
  const int w = tid >> 6;
  const int lane = tid & 63;

  const int gx = gridDim.x;
  const int bid = blockIdx.y * gx + blockIdx.x;
  const int nwg = gx * gridDim.y;
  const int logical = (bid & 7) * (nwg >> 3) + (bid >> 3);
  const int bm = (logical / gx) << 7;
  const int bn = (logical % gx) << 7;
  const int wr = w >> 1, wc = w & 1;

  const int r0 = (w << 4) + (lane >> 2);
  const int kc = (lane & 3) << 3;
  const u16* Ag0 = A + (size_t)(bm + r0) * K + kc;
  const u16* Ag1 = Ag0 + (size_t)64 * K;
  const u16* Bg0 = B + (size_t)(bn + r0) * K + kc;
  const u16* Bg1 = Bg0 + (size_t)64 * K;

  int aoff[4], boff[4];
#pragma unroll
  for (int m = 0; m < 4; ++m)
    aoff[m] = (((wr << 6) + (m << 4) + (lane & 15)) << 5) + ((lane >> 4) << 3);
#pragma unroll
  for (int n = 0; n < 4; ++n)
    boff[n] = (((wc << 6) + (n << 4) + (lane & 15)) << 5) + ((lane >> 4) << 3);

  f32x4 acc[4][4];
#pragma unroll
  for (int m = 0; m < 4; ++m)
#pragma unroll
    for (int n = 0; n < 4; ++n) acc[m][n] = (f32x4){0.f, 0.f, 0.f, 0.f};

#define STAGE(buf, kt)                                                        \
  {                                                                           \
    u16* as_ = As + (buf) * 4096 + (w << 9);                                  \
    u16* bs_ = Bs + (buf) * 4096 + (w << 9);                                  \
    __builtin_amdgcn_global_load_lds(                                         \
        (const __attribute__((address_space(1))) void*)(Ag0 + (kt)),          \
        (__attribute__((address_space(3))) void*)as_, 16, 0, 0);              \
    __builtin_amdgcn_global_load_lds(                                         \
        (const __attribute__((address_space(1))) void*)(Ag1 + (kt)),          \
        (__attribute__((address_space(3))) void*)(as_ + 2048), 16, 0, 0);     \
    __builtin_amdgcn_global_load_lds(                                         \
        (const __attribute__((address_space(1))) void*)(Bg0 + (kt)),          \
        (__attribute__((address_space(3))) void*)bs_, 16, 0, 0);              \
    __builtin_amdgcn_global_load_lds(                                         \
        (const __attribute__((address_space(1))) void*)(Bg1 + (kt)),          \
        (__attribute__((address_space(3))) void*)(bs_ + 2048), 16, 0, 0);     \
  }

  const int nt = K >> 5;
  STAGE(0, 0);
  int cur = 0;
  for (int t = 0; t < nt; ++t) {
    if (t + 1 < nt) {
      STAGE(cur ^ 1, (t + 1) << 5);
      B1_WAIT(4)
    } else {
      B1_WAIT(0)
    }
    const u16* Ab = As + cur * 4096;
    const u16* Bb = Bs + cur * 4096;
    bf16x8 af[4], bfr[4];
#pragma unroll
    for (int m = 0; m < 4; ++m) af[m] = *(const bf16x8*)(Ab + aoff[m]);
#pragma unroll
    for (int n = 0; n < 4; ++n) bfr[n] = *(const bf16x8*)(Bb + boff[n]);
#pragma unroll
    for (int m = 0; m < 4; ++m)
#pragma unroll
      for (int n = 0; n < 4; ++n)
        acc[m][n] = __builtin_amdgcn_mfma_f32_16x16x32_bf16(
            af[m], bfr[n], acc[m][n], 0, 0, 0);
    B2_BAR()
    cur ^= 1;
  }
#undef STAGE

  const int rb = bm + (wr << 6) + ((lane >> 4) << 2);
  const int cb = bn + (wc << 6) + (lane & 15);
#pragma unroll
  for (int m = 0; m < 4; ++m)
#pragma unroll
    for (int n = 0; n < 4; ++n) {
      int col = cb + (n << 4);
#pragma unroll
      for (int j = 0; j < 4; ++j) {
        size_t idx = (size_t)(rb + (m << 4) + j) * N + col;
        float v = acc[m][n][j];
        if (ACC) v += C[idx];
        if (WF32) C[idx] = v;
        if (WBF16) Cb[idx] = f2bf(v);
      }
    }
}

// ---------------------------------------------------------------------------
// bf16 MFMA GEMM, 128x64 tile for N=512 GEMMs, counted-vmcnt (3 loads/STAGE).
// ---------------------------------------------------------------------------
template <bool ACC, bool WF32, bool WBF16>
__global__ __launch_bounds__(256) void gemm_n64(
    const u16* __restrict__ A, const u16* __restrict__ B,
    float* __restrict__ C, u16* __restrict__ Cb, int M, int N, int K) {
  __shared__ u16 As[8192];  // [2][128][32]
  __shared__ u16 Bs[4096];  // [2][64][32]
  const int tid = threadIdx.x;
  const int w = tid >> 6;
  const int lane = tid & 63;

  const int gx = gridDim.x;  // N/64
  const int bid = blockIdx.y * gx + blockIdx.x;
  const int nwg = gx * gridDim.y;
  const int logical = (bid & 7) * (nwg >> 3) + (bid >> 3);
  const int bm = (logical / gx) << 7;
  const int bn = (logical % gx) << 6;

  const int r0 = (w << 4) + (lane >> 2);
  const int kc = (lane & 3) << 3;
  const u16* Ag0 = A + (size_t)(bm + r0) * K + kc;
  const u16* Ag1 = Ag0 + (size_t)64 * K;
  const u16* Bg0 = B + (size_t)(bn + r0) * K + kc;

  int aoff[2], boff[4];
#pragma unroll
  for (int m = 0; m < 2; ++m)
    aoff[m] = (((w << 5) + (m << 4) + (lane & 15)) << 5) + ((lane >> 4) << 3);
#pragma unroll
  for (int n = 0; n < 4; ++n)
    boff[n] = (((n << 4) + (lane & 15)) << 5) + ((lane >> 4) << 3);

  f32x4 acc[2][4];
#pragma unroll
  for (int m = 0; m < 2; ++m)
#pragma unroll
    for (int n = 0; n < 4; ++n) acc[m][n] = (f32x4){0.f, 0.f, 0.f, 0.f};

#define STAGE(buf, kt)                                                        \
  {                                                                           \
    u16* as_ = As + (buf) * 4096 + (w << 9);                                  \
    u16* bs_ = Bs + (buf) * 2048 + (w << 9);                                  \
    __builtin_amdgcn_global_load_lds(                                         \
        (const __attribute__((address_space(1))) void*)(Ag0 + (kt)),          \
        (__attribute__((address_space(3))) void*)as_, 16, 0, 0);              \
    __builtin_amdgcn_global_load_lds(                                         \
        (const __attribute__((address_space(1))) void*)(Ag1 + (kt)),          \
        (__attribute__((address_space(3))) void*)(as_ + 2048), 16, 0, 0);     \
    __builtin_amdgcn_global_load_lds(                                         \
        (const __attribute__((address_space(1))) void*)(Bg0 + (kt)),          \
        (__attribute__((address_space(3))) void*)bs_, 16, 0, 0);              \
  }

  const int nt = K >> 5;
  STAGE(0, 0);
  int cur = 0;
  for (int t = 0; t < nt; ++t) {
    if (t + 1 < nt) {
      STAGE(cur ^ 1, (t + 1) << 5);
      B1_WAIT(3)
    } else {
      B1_WAIT(0)
    }
    const u16* Ab = As + cur * 4096;
    const u16* Bb = Bs + cur * 2048;
    bf16x8 af[2], bfr[4];
#pragma unroll
    for (int m = 0; m < 2; ++m) af[m] = *(const bf16x8*)(Ab + aoff[m]);
#pragma unroll
    for (int n = 0; n < 4; ++n) bfr[n] = *(const bf16x8*)(Bb + boff[n]);
#pragma unroll
    for (int m = 0; m < 2; ++m)
#pragma unroll
      for (int n = 0; n < 4; ++n)
        acc[m][n] = __builtin_amdgcn_mfma_f32_16x16x32_bf16(
            af[m], bfr[n], acc[m][n], 0, 0, 0);
    B2_BAR()
    cur ^= 1;
  }
#undef STAGE

  const int rb = bm + (w << 5) + ((lane >> 4) << 2);
  const int cb = bn + (lane & 15);
#pragma unroll
  for (int m = 0; m < 2; ++m)
#pragma unroll
    for (int n = 0; n < 4; ++n) {
      int col = cb + (n << 4);
#pragma unroll
      for (int j = 0; j < 4; ++j) {
        size_t idx = (size_t)(rb + (m << 4) + j) * N + col;
        float v = acc[m][n][j];
        if (ACC) v += C[idx];
        if (WF32) C[idx] = v;
        if (WBF16) Cb[idx] = f2bf(v);
      }
    }
}

// ---------------------------------------------------------------------------
// LayerNorm over DT=512 per row; writes bf16 q_txt
// ---------------------------------------------------------------------------
__global__ __launch_bounds__(256) void ln_kernel(
    const float* __restrict__ m, const float* __restrict__ g,
    const float* __restrict__ bta, u16* __restrict__ q) {
  int row = blockIdx.x;
  int tid = threadIdx.x;
  float v0 = m[(size_t)row * 512 + tid];
  float v1 = m[(size_t)row * 512 + 256 + tid];
  __shared__ float red[4], red2[4];
  float s = v0 + v1;
#pragma unroll
  for (int d = 32; d; d >>= 1) s += __shfl_xor(s, d);
  if ((tid & 63) == 0) red[tid >> 6] = s;
  __syncthreads();
  float mu = (red[0] + red[1] + red[2] + red[3]) * (1.0f / 512.0f);
  float d0 = v0 - mu, d1 = v1 - mu;
  float s2 = d0 * d0 + d1 * d1;
#pragma unroll
  for (int d = 32; d; d >>= 1) s2 += __shfl_xor(s2, d);
  if ((tid & 63) == 0) red2[tid >> 6] = s2;
  __syncthreads();
  float var = (red2[0] + red2[1] + red2[2] + red2[3]) * (1.0f / 512.0f);
  float r = rsqrtf(var + 1e-5f);
  q[(size_t)row * 512 + tid] = f2bf(d0 * r * g[tid] + bta[tid]);
  q[(size_t)row * 512 + 256 + tid] = f2bf(d1 * r * g[tid + 256] + bta[tid + 256]);
}

// ---------------------------------------------------------------------------
// MFMA banded attention. Block = (b, 16 l), 512 threads = 8 waves.
// ---------------------------------------------------------------------------
__global__ __launch_bounds__(512) void attn_kernel(
    const u16* __restrict__ Qb, const u16* __restrict__ KV,
    const float* __restrict__ alpha_p, float* __restrict__ A,
    u16* __restrict__ Fv) {
  __shared__ u16 KV_s[96 * 512];   // 96 KB, K then reused for V
  __shared__ u16 Q_s[16 * 520];    // padded stride 520 u16
  __shared__ float S_s[16 * 100];  // logits then attention weights

  const int bid = blockIdx.x;
  const int logical = (bid & 7) * 64 + (bid >> 3);
  const int b = logical >> 4, lg = logical & 15;
  const int l0 = lg * 16;
  const int tid = threadIdx.x;
  const int w = tid >> 6, lane = tid & 63;
  const float al = *alpha_p;

  const int c_min = (1023 * l0) / 255;
  const int kb0 = min(max(c_min - BAND_, 0), N_ - 96);

  {
    const size_t rowb = (size_t)(b * N_ + kb0);
    for (int rr = 0; rr < 12; ++rr) {
      const int r = w * 12 + rr;
      const u16* src = KV + (rowb + r) * 1024 + ((lane * 8) ^ ((r & 7) << 3));
      u16* dst = KV_s + r * 512;
      __builtin_amdgcn_global_load_lds(
          (const __attribute__((address_space(1))) void*)src,
          (__attribute__((address_space(3))) void*)dst, 16, 0, 0);
    }
  }
  {
    const int r = tid >> 5;
    const u16* qrow = Qb + (size_t)(b * L_ + l0 + r) * 512;
#pragma unroll
    for (int h = 0; h < 2; ++h) {
      const int ch = (tid & 31) + h * 32;
      u16x8 v = *(const u16x8*)(qrow + ch * 8);
      *(u16x8*)(Q_s + r * 520 + ch * 8) = v;
    }
  }
  __syncthreads();

  if (w < 6) {
    f32x4 acc = {0.f, 0.f, 0.f, 0.f};
    const int arow = (lane & 15) * 520 + ((lane >> 4) << 3);
    const int key = w * 16 + (lane & 15);
    const int swz = (key & 7) << 3;
    for (int ks = 0; ks < 16; ++ks) {
      bf16x8 aq = *(const bf16x8*)(Q_s + arow + ks * 32);
      bf16x8 bk =
          *(const bf16x8*)(KV_s + key * 512 + ((ks * 32 + ((lane >> 4) << 3)) ^ swz));
      acc = __builtin_amdgcn_mfma_f32_16x16x32_bf16(aq, bk, acc, 0, 0, 0);
    }
#pragma unroll
    for (int j = 0; j < 4; ++j)
      S_s[((lane >> 4) * 4 + j) * 100 + w * 16 + (lane & 15)] = acc[j];
  }
  __syncthreads();

  {
    const size_t rowb = (size_t)(b * N_ + kb0);
    for (int rr = 0; rr < 12; ++rr) {
      const int r = w * 12 + rr;
      const u16* src =
          KV + (rowb + r) * 1024 + 512 + ((lane * 8) ^ ((r & 7) << 3));
      u16* dst = KV_s + r * 512;
      __builtin_amdgcn_global_load_lds(
          (const __attribute__((address_space(1))) void*)src,
          (__attribute__((address_space(3))) void*)dst, 16, 0, 0);
    }
  }

#pragma unroll
  for (int rr = 0; rr < 2; ++rr) {
    const int l = 2 * w + rr;
    const int c = (1023 * (l0 + l)) / 255;
    const int g0 = kb0 + lane, g1 = kb0 + 64 + lane;
    const bool v0 = (g0 >= c - BAND_) && (g0 <= c + BAND_);
    const bool v1 = (lane < 32) && (g1 >= c - BAND_) && (g1 <= c + BAND_);
    const float sc = 0.044194173824159216f;
    float x0 = v0 ? S_s[l * 100 + lane] * sc +
                        al * ((float)(c - g0) * (1.0f / 16.000001f))
                  : -INFINITY;
    float x1 = v1 ? S_s[l * 100 + 64 + lane] * sc +
                        al * ((float)(c - g1) * (1.0f / 16.000001f))
                  : -INFINITY;
    float mx = fmaxf(x0, x1);
#pragma unroll
    for (int d = 32; d; d >>= 1) mx = fmaxf(mx, __shfl_xor(mx, d));
    float e0 = v0 ? expf(x0 - mx) : 0.0f;
    float e1 = v1 ? expf(x1 - mx) : 0.0f;
    float sm = e0 + e1;
#pragma unroll
    for (int d = 32; d; d >>= 1) sm += __shfl_xor(sm, d);
    const float inv = 1.0f / sm;
    S_s[l * 100 + lane] = e0 * inv;
    if (lane < 32) S_s[l * 100 + 64 + lane] = e1 * inv;
    const int lo = max(0, c - BAND_), hi = min(N_ - 1, c + BAND_);
    float* Arow = A + (size_t)(b * L_ + l0 + l) * N_;
#pragma unroll
    for (int p4 = 0; p4 < 4; ++p4) {
      const int p = (p4 * 64 + lane) * 4;
      float4 v;
      v.x = (p + 0 >= lo && p + 0 <= hi) ? S_s[l * 100 + p + 0 - kb0] : 0.0f;
      v.y = (p + 1 >= lo && p + 1 <= hi) ? S_s[l * 100 + p + 1 - kb0] : 0.0f;
      v.z = (p + 2 >= lo && p + 2 <= hi) ? S_s[l * 100 + p + 2 - kb0] : 0.0f;
      v.w = (p + 3 >= lo && p + 3 <= hi) ? S_s[l * 100 + p + 3 - kb0] : 0.0f;
      ((float4*)Arow)[p4 * 64 + lane] = v;
    }
  }
  __syncthreads();

#pragma unroll
  for (int rr = 0; rr < 2; ++rr) {
    const int l = 2 * w + rr;
    const int c = (1023 * (l0 + l)) / 255;
    const int jlo = max(0, c - BAND_) - kb0, jhi = min(N_ - 1, c + BAND_) - kb0;
    float acc[8] = {};
    for (int j = jlo; j <= jhi; ++j) {
      const float avj = S_s[l * 100 + j];
      const u16x8 v =
          *(const u16x8*)(KV_s + j * 512 + ((lane * 8) ^ ((j & 7) << 3)));
#pragma unroll
      for (int t = 0; t < 8; ++t) acc[t] += avj * bf2f(v[t]);
    }
    u16x8 fo;
#pragma unroll
    for (int t = 0; t < 8; ++t) fo[t] = f2bf(acc[t]);
    *(u16x8*)(Fv + (size_t)(b * L_ + l0 + l) * 512 + lane * 8) = fo;
  }
}

// ---------------------------------------------------------------------------
extern "C" void kernel_launch(void* const* d_in, const int* in_sizes, int n_in,
                              void* d_out, int out_size, void* d_ws,
                              size_t ws_size, hipStream_t stream) {
  const float* vis = (const float*)d_in[0];    // [32,1024,512]
  const int* ids = (const int*)d_in[1];        // [32,256,8]
  const float* emb = (const float*)d_in[2];    // [1024,512]
  const float* wq = (const float*)d_in[3];     // [512,512]
  const float* wk = (const float*)d_in[4];     // [512,512]
  const float* wvp = (const float*)d_in[5];    // [512,512]
  const float* wv2t = (const float*)d_in[6];   // [512,512]
  const float* dwk = (const float*)d_in[7];    // [512,1,3]
  const float* pwk = (const float*)d_in[8];    // [512,512,1]
  const float* lng = (const float*)d_in[9];    // [512]
  const float* lnb = (const float*)d_in[10];   // [512]
  const float* alpha = (const float*)d_in[11]; // scalar

  float* out_cls = (float*)d_out;                // [8192,1024]
  float* out_H = out_cls + (size_t)8192 * 1024;  // [8192,512]
  float* out_A = out_H + (size_t)8192 * 512;     // [8192,1024]

  // workspace layout
  char* p = (char*)d_ws;
  u16* KVb  = (u16*)p;              p += (size_t)32768 * 1024 * 2;
  u16* embb = (u16*)p;              p += (size_t)1024 * 512 * 2;
  u16* wqb  = (u16*)p;              p += (size_t)512 * 512 * 2;
  u16* wkvb = (u16*)p;              p += (size_t)1024 * 512 * 2;
  u16* wv2tb= (u16*)p;              p += (size_t)512 * 512 * 2;
  u16* pwkb = (u16*)p;              p += (size_t)512 * 512 * 2;
  u16* shmb = (u16*)p;              p += (size_t)8192 * 512 * 2;
  float* mbuf = (float*)p;          p += (size_t)8192 * 512 * 4;
  u16* qbuf = (u16*)p;              p += (size_t)8192 * 512 * 2;
  u16* Qbf  = (u16*)p;              p += (size_t)8192 * 512 * 2;
  u16* Fvb  = (u16*)p;              p += (size_t)8192 * 512 * 2;
  u16* Hb   = (u16*)p;              p += (size_t)8192 * 512 * 2;

  // small weights -> bf16
  cvt_weights<<<1792, 256, 0, stream>>>(emb, wq, wk, wvp, wv2t, pwk,
                                        embb, wqb, wkvb, wv2tb, pwkb);

  // KV = vis_f32 @ [wk;wv]^T  -> bf16 [32768][1024]  (fused convert, LDS-f32)
  gemm_kv_f32a<<<dim3(8, 256), 256, 0, stream>>>(
      vis, wkvb, KVb, 32768, 1024, 512);

  // text front: gather + dwconv + silu + means
  text_front<<<8192, 256, 0, stream>>>(ids, emb, dwk, shmb, mbuf);
  // m += shm_mean @ pw^T  (pointwise conv folded through mean)
  gemm_n64<true, true, false><<<dim3(8, 64), 256, 0, stream>>>(
      shmb, pwkb, mbuf, nullptr, 8192, 512, 512);
  // LayerNorm -> q_txt (bf16)
  ln_kernel<<<8192, 256, 0, stream>>>(mbuf, lng, lnb, qbuf);
  // Q = q_txt @ wq^T (bf16 out)
  gemm_n64<false, false, true><<<dim3(8, 64), 256, 0, stream>>>(
      qbuf, wqb, nullptr, Qbf, 8192, 512, 512);
  // banded attention (MFMA) -> A (full rows, f32), Fv (bf16)
  attn_kernel<<<512, 512, 0, stream>>>(Qbf, KVb, alpha, out_A, Fvb);
  // H = Fv @ wv2t^T (f32 out + bf16 copy)
  gemm_n64<false, true, true><<<dim3(8, 64), 256, 0, stream>>>(
      Fvb, wv2tb, out_H, Hb, 8192, 512, 512);
  // cls = H @ emb^T (f32 out)
  gemm_mfma<false, true, false><<<dim3(8, 64), 256, 0, stream>>>(
      Hb, embb, out_cls, nullptr, 8192, 1024, 512);
}